// Round 7
// baseline (346.246 us; speedup 1.0000x reference)
//
#include <hip/hip_runtime.h>
#include <hip/hip_bf16.h>

typedef __bf16 bf16_t;
typedef bf16_t bf16x8 __attribute__((ext_vector_type(8)));
typedef bf16_t bf16x4 __attribute__((ext_vector_type(4)));
typedef float f32x4 __attribute__((ext_vector_type(4)));

// H=8 D=31 T=4 P=50 C=248 O=744 B=512, DT=124, SCALE=31^-0.5
constexpr float SCALE = 0.17960530202677491f;

// LDS layout (byte offsets). Shrunk arrays rely on masked garbage reads:
//  QH [50][128] bf16 swz(row&7)      @0      (12800)  q, pre-scaled by SCALE
//  KH [50][128] bf16 swz(row&7)      @12800  (12800)
//  AS [2][50][64] bf16 swz(row&7)    @25600  (12800)  attn probs, dbuf
//  VT [2][124][64] bf16 swz(r>>2&7)  @38400  (31744)  v^T, dbuf, cols 50-63 zeroed
//  LS [50][52] f32                   @70144  (10400)  logits
#define QH_OFF 0
#define KH_OFF 12800
#define AS_OFF 25600
#define VT_OFF 38400
#define LS_OFF 70144
#define SMEM_TOTAL 80544

__device__ __forceinline__ f32x4 mfma16(bf16x8 a, bf16x8 b, f32x4 c) {
    return __builtin_amdgcn_mfma_f32_16x16x32_bf16(a, b, c, 0, 0, 0);
}
__device__ __forceinline__ void fence() {
    asm volatile("s_waitcnt lgkmcnt(0)" ::: "memory");
}
__device__ __forceinline__ void opaque(bf16x8& v) {
    asm volatile("" : "+v"(v));
}

// ---------------------------------------------------------------------------
// prep: W -> per-(head,mtile,kstep) fragment-contiguous, rel -> frag blocks
// (rt 0..6, rows 99..111 zero), bias -> bp[h][96].
// ---------------------------------------------------------------------------
__global__ void prep_kernel(const float* __restrict__ w, const float* __restrict__ b_qkv,
                            const float* __restrict__ rel,
                            bf16_t* __restrict__ Wf, bf16_t* __restrict__ relf,
                            float* __restrict__ bp)
{
    int i = blockIdx.x * 256 + threadIdx.x;
    if (i < 196608) {                    // Wf
        int e = i & 7, lane = (i >> 3) & 63;
        int f = i >> 9;                  // (h*6+m)*8+ks
        int ks = f & 7, g = f >> 3;
        int h = g / 6, m = g - h * 6;
        int r15 = lane & 15, g4 = lane >> 4;
        int s = m >> 1, d = ((m & 1) << 4) + r15;
        int c = ks * 32 + g4 * 8 + e;
        float v = 0.f;
        if (d < 31 && c < 248) v = w[(long)(s * 248 + h * 31 + d) * 248 + c];
        Wf[i] = (bf16_t)v;
        return;
    }
    i -= 196608;
    if (i < 14336) {                     // relf: rt 0..6
        int e = i & 7, lane = (i >> 3) & 63;
        int f = i >> 9;                  // rt*4+ks
        int ks = f & 3, rt = f >> 2;
        int r = rt * 16 + (lane & 15);
        int dt = ks * 32 + (lane >> 4) * 8 + e;
        float v = 0.f;
        if (r < 99 && dt < 124) v = rel[r * 124 + dt];
        relf[i] = (bf16_t)v;
        return;
    }
    i -= 14336;
    if (i < 768) {                       // bp[h][96]
        int h = i / 96, row = i - h * 96;
        int s = row >> 5, d = row & 31;
        bp[i] = (d < 31) ? b_qkv[s * 248 + h * 31 + d] : 0.f;
    }
}

// ---------------------------------------------------------------------------
// Fused kernel: one block per batch b. 512 threads = 8 waves, 80.5 KB LDS
// -> 2 blocks/CU. Head-pipelined: per iter {all: qkv(it)} bar
// {w0-3: scores+softmax(it) || w4-7: PV(it-1)} bar. 2 barriers/iter.
// ---------------------------------------------------------------------------
__global__ void __launch_bounds__(512, 4)
fused_kernel(const float* __restrict__ x, const bf16_t* __restrict__ Wf,
             const bf16_t* __restrict__ relf, const float* __restrict__ bp,
             float* __restrict__ out)
{
    __shared__ __align__(16) char smem[SMEM_TOTAL];
    const int b    = blockIdx.x;
    const int tid  = threadIdx.x;
    const int lane = tid & 63;
    const int w    = tid >> 6;           // 0..7
    const int r15  = lane & 15, g4 = lane >> 4;

    // ---- phase 0: zero pads ----
    {
        f32x4 z = f32x4{0.f, 0.f, 0.f, 0.f};
#pragma unroll
        for (int k4 = 0; k4 < 4; ++k4) {             // both VT buffers fully
            int idx = tid + k4 * 512;
            if (idx < 1984) *(f32x4*)(smem + VT_OFF + idx * 16) = z;
        }
        if (tid < 100) {                             // QH/KH dt-pad cols 124..127
            int row = tid >> 1;
            char* base = smem + ((tid & 1) ? KH_OFF : QH_OFF);
            int chunk = 15 ^ (row & 7);
            *(long*)(base + row * 256 + chunk * 16 + 8) = 0L;
        }
    }

    // ---- phase 1: A fragments from global x (persistent) ----
    const float* xb = x + (long)b * 49600;
    const bool t1ok = (w + 8) <= 12;     // n-tiles 8..12 real; 13..15 dead
    bf16x8 Areg[2][8];
#pragma unroll
    for (int ui = 0; ui < 2; ++ui) {
        int n = (w + 8 * ui) * 16 + r15;
        const float* xn = xb + n;
        bool nok = (n < 200);
#pragma unroll
        for (int ks = 0; ks < 8; ++ks) {
            bf16x8 fr;
#pragma unroll
            for (int e = 0; e < 8; ++e) {
                int c = ks * 32 + g4 * 8 + e;
                float v = (nok && c < 248) ? xn[(long)c * 200] : 0.f;
                fr[e] = (bf16_t)v;
            }
            Areg[ui][ks] = fr;
        }
    }
#pragma unroll
    for (int ui = 0; ui < 2; ++ui)
#pragma unroll
        for (int ks = 0; ks < 8; ++ks)
            opaque(Areg[ui][ks]);
    __syncthreads();

    // ---- head-pipelined loop: 9 iterations ----
    for (int it = 0; it <= 8; ++it) {
        const int cur = it & 1, prv = cur ^ 1;

        if (it < 8) {
            // ======== qkv(it): all waves ========
            const bf16_t* wf = Wf + ((long)(it * 48) << 9) + lane * 8;
            char* VTc = smem + VT_OFF + cur * 15872;
            bf16x8 B0[4];
#pragma unroll
            for (int k4 = 0; k4 < 4; ++k4)
                B0[k4] = *(const bf16x8*)(wf + (k4 << 9));
#pragma unroll
            for (int m = 0; m < 6; ++m) {
                bf16x8 B1[4];
#pragma unroll
                for (int k4 = 0; k4 < 4; ++k4)
                    B1[k4] = *(const bf16x8*)(wf + ((m * 8 + 4 + k4) << 9));
                f32x4 acc0 = f32x4{0.f, 0.f, 0.f, 0.f};
                f32x4 acc1 = f32x4{0.f, 0.f, 0.f, 0.f};
#pragma unroll
                for (int k4 = 0; k4 < 4; ++k4) {
                    acc0 = mfma16(Areg[0][k4], B0[k4], acc0);
                    if (t1ok) acc1 = mfma16(Areg[1][k4], B0[k4], acc1);
                }
                if (m < 5) {
#pragma unroll
                    for (int k4 = 0; k4 < 4; ++k4)
                        B0[k4] = *(const bf16x8*)(wf + (((m + 1) * 8 + k4) << 9));
                }
#pragma unroll
                for (int k4 = 0; k4 < 4; ++k4) {
                    acc0 = mfma16(Areg[0][4 + k4], B1[k4], acc0);
                    if (t1ok) acc1 = mfma16(Areg[1][4 + k4], B1[k4], acc1);
                }
                int s = m >> 1;
                int d = ((m & 1) << 4) + r15;        // 0..31
                float bias = bp[it * 96 + m * 16 + r15];
                if (d < 31) {
#pragma unroll
                    for (int ui = 0; ui < 2; ++ui) {
                        if (ui == 1 && !t1ok) continue;
                        f32x4 a = ui ? acc1 : acc0;
                        int p = (w + 8 * ui) * 4 + g4;
                        if (p >= 50) continue;
                        float a0 = a[0] + bias, a1 = a[1] + bias;
                        float a2 = a[2] + bias, a3 = a[3] + bias;
                        if (s == 0) { a0 *= SCALE; a1 *= SCALE; a2 *= SCALE; a3 *= SCALE; }
                        if (s < 2) {
                            bf16x4 pk = {(bf16_t)a0, (bf16_t)a1, (bf16_t)a2, (bf16_t)a3};
                            char* base = smem + (s == 0 ? QH_OFF : KH_OFF);
                            int chunk = (d >> 1) ^ (p & 7);
                            *(bf16x4*)(base + p * 256 + chunk * 16 + ((d & 1) << 3)) = pk;
                        } else {
                            int chunkb = ((p >> 3) ^ (d & 7)) << 4;
                            char* vb = VTc + (d * 4) * 128 + chunkb + (p & 7) * 2;
                            *(bf16_t*)(vb)       = (bf16_t)a0;
                            *(bf16_t*)(vb + 128) = (bf16_t)a1;
                            *(bf16_t*)(vb + 256) = (bf16_t)a2;
                            *(bf16_t*)(vb + 384) = (bf16_t)a3;
                        }
                    }
                }
            }
        }
        __syncthreads();

        if (w < 4) {
            if (it < 8) {
                // ======== scores + softmax(it): wave w owns q-tile w ========
                const int qt = w;
                bf16x8 Afr[4];
                {
                    int p = qt * 16 + r15;
                    int hp = p & 7;
#pragma unroll
                    for (int ks = 0; ks < 4; ++ks)
                        Afr[ks] = *(const bf16x8*)(smem + QH_OFF + p * 256 + ((((ks << 2) | g4) ^ hp) << 4));
                }
                // dots (q pre-scaled)
#pragma unroll
                for (int ct = 0; ct < 4; ++ct) {
                    int c = ct * 16 + r15;
                    int hc = c & 7;
                    f32x4 sA = f32x4{0.f, 0.f, 0.f, 0.f};
#pragma unroll
                    for (int ks = 0; ks < 4; ++ks) {
                        bf16x8 Bf = *(const bf16x8*)(smem + KH_OFF + c * 256 + ((((ks << 2) | g4) ^ hc) << 4));
                        sA = mfma16(Afr[ks], Bf, sA);
                    }
                    if (c < 50) {
#pragma unroll
                        for (int j = 0; j < 4; ++j) {
                            int qrow = qt * 16 + g4 * 4 + j;
                            if (qrow < 50)
                                *(float*)(smem + LS_OFF + (qrow * 52 + c) * 4) = sA[j];
                        }
                    }
                }
                fence();
                // rel bias, rolling prefetch; jj = r + qrow - 49
                {
                    const bf16_t* rf = relf + lane * 8;
                    bf16x8 R0[4];
#pragma unroll
                    for (int ks = 0; ks < 4; ++ks) R0[ks] = *(const bf16x8*)(rf + (ks << 9));
                    for (int rt = 0; rt < 7; ++rt) {
                        bf16x8 R1[4];
                        if (rt < 6) {
#pragma unroll
                            for (int ks = 0; ks < 4; ++ks)
                                R1[ks] = *(const bf16x8*)(rf + (((rt + 1) * 4 + ks) << 9));
                        }
                        f32x4 sA = f32x4{0.f, 0.f, 0.f, 0.f};
#pragma unroll
                        for (int ks = 0; ks < 4; ++ks) sA = mfma16(Afr[ks], R0[ks], sA);
                        int r = rt * 16 + r15;
#pragma unroll
                        for (int j = 0; j < 4; ++j) {
                            int qrow = qt * 16 + g4 * 4 + j;
                            int jj = r + qrow - 49;
                            if (qrow < 50 && jj >= 0 && jj < 50)
                                *(float*)(smem + LS_OFF + (qrow * 52 + jj) * 4) += sA[j];
                        }
#pragma unroll
                        for (int ks = 0; ks < 4; ++ks) R0[ks] = R1[ks];
                    }
                }
                fence();
                // softmax: 4 lanes/row over this wave's 16 rows
                {
                    int row = qt * 16 + (lane >> 2);
                    int quad = lane & 3;
                    char* ASc = smem + AS_OFF + cur * 6400;
                    if (row < 50) {
                        float mx = -1e30f;
                        for (int jj = quad; jj < 50; jj += 4)
                            mx = fmaxf(mx, *(const float*)(smem + LS_OFF + (row * 52 + jj) * 4));
                        mx = fmaxf(mx, __shfl_xor(mx, 1));
                        mx = fmaxf(mx, __shfl_xor(mx, 2));
                        float sum = 0.f;
                        for (int jj = quad; jj < 50; jj += 4) {
                            float* pL = (float*)(smem + LS_OFF + (row * 52 + jj) * 4);
                            float e = __expf(*pL - mx);
                            *pL = e;
                            sum += e;
                        }
                        sum += __shfl_xor(sum, 1);
                        sum += __shfl_xor(sum, 2);
                        float rs = 1.f / sum;
                        int hrow = row & 7;
                        for (int jj = quad; jj < 64; jj += 4) {
                            float v = (jj < 50)
                                ? *(const float*)(smem + LS_OFF + (row * 52 + jj) * 4) * rs : 0.f;
                            *(bf16_t*)(ASc + row * 128 + (((jj >> 3) ^ hrow) << 4) + (jj & 7) * 2) = (bf16_t)v;
                        }
                    }
                }
            }
        } else {
            if (it > 0) {
                // ======== PV(it-1): waves 4..7, 2 i-tiles each ========
                const int hh = it - 1;
                const int wv = w - 4;
                const char* VTp = smem + VT_OFF + prv * 15872;
                const char* ASp = smem + AS_OFF + prv * 6400;
#pragma unroll
                for (int ii = 0; ii < 2; ++ii) {
                    int itile = wv * 2 + ii;
                    int irow = itile * 16 + r15;
                    int hv = (irow >> 2) & 7;
                    bf16x8 Av[2];
#pragma unroll
                    for (int ks = 0; ks < 2; ++ks)
                        Av[ks] = *(const bf16x8*)(VTp + irow * 128 + ((((ks << 2) | g4) ^ hv) << 4));
                    int dd = itile * 4 + g4;
#pragma unroll
                    for (int pt = 0; pt < 4; ++pt) {
                        int prow = pt * 16 + r15;
                        int hp2 = prow & 7;
                        f32x4 po = f32x4{0.f, 0.f, 0.f, 0.f};
#pragma unroll
                        for (int ks = 0; ks < 2; ++ks) {
                            bf16x8 Bs = *(const bf16x8*)(ASp + prow * 128 + ((((ks << 2) | g4) ^ hp2) << 4));
                            po = mfma16(Av[ks], Bs, po);
                        }
                        if (dd < 31 && prow < 50)
                            *(f32x4*)(out + ((long)b * 248 + hh * 31 + dd) * 200 + prow * 4) = po;
                    }
                }
            }
        }
        __syncthreads();
    }
}

// ---------------------------------------------------------------------------
extern "C" void kernel_launch(void* const* d_in, const int* in_sizes, int n_in,
                              void* d_out, int out_size, void* d_ws, size_t ws_size,
                              hipStream_t stream)
{
    const float* x   = (const float*)d_in[0];
    const float* wq  = (const float*)d_in[1];
    const float* bq  = (const float*)d_in[2];
    const float* rel = (const float*)d_in[3];
    float* out = (float*)d_out;

    char* ws = (char*)d_ws;
    bf16_t* Wf   = (bf16_t*)ws;                    // 196,608 elems = 393,216 B
    bf16_t* relf = (bf16_t*)(ws + 393216);         // 14,336 elems  = 28,672 B
    float*  bp   = (float*)(ws + 421888);          // 768 f32       = 3,072 B

    const int B = in_sizes[0] / 49600;

    prep_kernel<<<dim3(828), dim3(256), 0, stream>>>(wq, bq, rel, Wf, relf, bp);
    fused_kernel<<<dim3(B), dim3(512), 0, stream>>>(x, Wf, relf, bp, out);
}

// Round 8
// 266.954 us; speedup vs baseline: 1.2970x; 1.2970x over previous
//
#include <hip/hip_runtime.h>
#include <hip/hip_bf16.h>

typedef __bf16 bf16_t;
typedef bf16_t bf16x8 __attribute__((ext_vector_type(8)));
typedef bf16_t bf16x4 __attribute__((ext_vector_type(4)));
typedef float f32x4 __attribute__((ext_vector_type(4)));

// H=8 D=31 T=4 P=50 C=248 O=744 B=512, DT=124, SCALE=31^-0.5
constexpr float SCALE = 0.17960530202677491f;

__device__ __forceinline__ f32x4 mfma16(bf16x8 a, bf16x8 b, f32x4 c) {
    return __builtin_amdgcn_mfma_f32_16x16x32_bf16(a, b, c, 0, 0, 0);
}
__device__ __forceinline__ void fence() {
    asm volatile("s_waitcnt lgkmcnt(0)" ::: "memory");
}

// ---------------------------------------------------------------------------
// prep: W -> per-(head,mtile,kstep) fragment-contiguous (rows d>=31 zero,
// cols c>=248 zero), rel -> frag blocks (rt 0..6, rows 99..111 zero).
// ---------------------------------------------------------------------------
__global__ void prep_kernel(const float* __restrict__ w, const float* __restrict__ rel,
                            bf16_t* __restrict__ Wf, bf16_t* __restrict__ relf)
{
    int i = blockIdx.x * 256 + threadIdx.x;
    if (i < 196608) {                    // Wf
        int e = i & 7, lane = (i >> 3) & 63;
        int f = i >> 9;                  // (h*6+m)*8+ks
        int ks = f & 7, g = f >> 3;
        int h = g / 6, m = g - h * 6;
        int r15 = lane & 15, g4 = lane >> 4;
        int s = m >> 1, d = ((m & 1) << 4) + r15;
        int c = ks * 32 + g4 * 8 + e;
        float v = 0.f;
        if (d < 31 && c < 248) v = w[(long)(s * 248 + h * 31 + d) * 248 + c];
        Wf[i] = (bf16_t)v;
        return;
    }
    i -= 196608;
    if (i < 14336) {                     // relf: rt 0..6
        int e = i & 7, lane = (i >> 3) & 63;
        int f = i >> 9;                  // rt*4+ks
        int ks = f & 3, rt = f >> 2;
        int r = rt * 16 + (lane & 15);
        int dt = ks * 32 + (lane >> 4) * 8 + e;
        float v = 0.f;
        if (r < 99 && dt < 124) v = rel[r * 124 + dt];
        relf[i] = (bf16_t)v;
    }
}

// ---------------------------------------------------------------------------
// qkv GEMM: block = 64 flat cols (f = b*200 + p*4 + t), all 768 o-rows.
// 512 thr = 8 waves; wave w = head w (6 m-tiles), 4 n-tiles from LDS.
// x read once; W read once per block (frag-packed, L2).
// Outputs (bf16): qb/kb [bh][64p][128i] (q pre-scaled), vb [bh][128i][64p].
// ---------------------------------------------------------------------------
__global__ void __launch_bounds__(512)
qkv_kernel(const float* __restrict__ x, const float* __restrict__ bqkv,
           const bf16_t* __restrict__ Wf, bf16_t* __restrict__ qb,
           bf16_t* __restrict__ kb, bf16_t* __restrict__ vb)
{
    __shared__ __align__(16) char XS[64 * 512];   // [col][256 K] bf16, swizzled
    const int tid  = threadIdx.x;
    const int lane = tid & 63;
    const int w    = tid >> 6;            // 0..7 = head
    const int r15  = lane & 15, g4 = lane >> 4;
    const int f0   = blockIdx.x * 64;

    // ---- stage x cols -> XS bf16 ----
    {
        const int cl = tid & 63;          // column within block
        const int cg = tid >> 6;          // 0..7
        long f = (long)f0 + cl;
        int bb = (int)(f / 200);
        int nn = (int)(f - (long)bb * 200);
        const float* xp = x + (long)bb * 49600 + nn;
#pragma unroll
        for (int ii = 0; ii < 4; ++ii) {
            int cb = cg + 8 * ii;         // 16B chunk index 0..31
            bf16x8 pk;
#pragma unroll
            for (int e = 0; e < 8; ++e) {
                int c = cb * 8 + e;
                float v = (c < 248) ? xp[(long)c * 200] : 0.f;
                pk[e] = (bf16_t)v;
            }
            *(bf16x8*)(XS + cl * 512 + ((cb ^ (cl & 7)) << 4)) = pk;
        }
    }
    __syncthreads();

    // ---- GEMM: acc[m 0..5][nt 0..3] ----
    const bf16_t* wf = Wf + ((long)(w * 48) << 9) + lane * 8;
    f32x4 acc[6][4];
#pragma unroll
    for (int m = 0; m < 6; ++m)
#pragma unroll
        for (int nt = 0; nt < 4; ++nt) acc[m][nt] = f32x4{0.f, 0.f, 0.f, 0.f};

    for (int ks = 0; ks < 8; ++ks) {
        bf16x8 Af[4];
#pragma unroll
        for (int nt = 0; nt < 4; ++nt) {
            int row = nt * 16 + r15;
            Af[nt] = *(const bf16x8*)(XS + row * 512 + ((((ks << 2) | g4) ^ (row & 7)) << 4));
        }
        bf16x8 Wr[6];
#pragma unroll
        for (int m = 0; m < 6; ++m)
            Wr[m] = *(const bf16x8*)(wf + ((m * 8 + ks) << 9));
#pragma unroll
        for (int m = 0; m < 6; ++m)
#pragma unroll
            for (int nt = 0; nt < 4; ++nt)
                acc[m][nt] = mfma16(Af[nt], Wr[m], acc[m][nt]);
    }

    // ---- epilogue ----
#pragma unroll
    for (int m = 0; m < 6; ++m) {
        int s = m >> 1;
        int d = ((m & 1) << 4) + r15;     // 0..31; d==31 -> acc 0, bias 0
        float bias = (d < 31) ? bqkv[s * 248 + w * 31 + d] : 0.f;
#pragma unroll
        for (int nt = 0; nt < 4; ++nt) {
            int n0 = f0 + nt * 16 + g4 * 4;
            int bb = n0 / 200;
            int nn = n0 - bb * 200;
            int p  = nn >> 2;             // 0..49 (t = element j)
            long bh = (long)bb * 8 + w;
            f32x4 a = acc[m][nt];
            float a0 = a[0] + bias, a1 = a[1] + bias, a2 = a[2] + bias, a3 = a[3] + bias;
            if (s == 0) { a0 *= SCALE; a1 *= SCALE; a2 *= SCALE; a3 *= SCALE; }
            if (s < 2) {
                bf16x4 pk = {(bf16_t)a0, (bf16_t)a1, (bf16_t)a2, (bf16_t)a3};
                bf16_t* dst = (s == 0 ? qb : kb) + (bh * 64 + p) * 128 + d * 4;
                *(bf16x4*)dst = pk;
            } else {
                bf16_t* dst = vb + (bh * 128 + d * 4) * 64 + p;
                dst[0]   = (bf16_t)a0;
                dst[64]  = (bf16_t)a1;
                dst[128] = (bf16_t)a2;
                dst[192] = (bf16_t)a3;
            }
        }
    }
}

// ---------------------------------------------------------------------------
// Attention: 1 block per (b,h), 256 thr = 4 waves, ~19 KB LDS (high occup.).
// Wave w owns q-tile w end-to-end: dots + rel scatter + softmax; then PV.
// ---------------------------------------------------------------------------
__global__ void __launch_bounds__(256)
attn_kernel(const bf16_t* __restrict__ qb, const bf16_t* __restrict__ kb,
            const bf16_t* __restrict__ vb, const bf16_t* __restrict__ relf,
            float* __restrict__ out)
{
    __shared__ float LS[50][52];
    __shared__ __align__(16) char AS[64 * 128];   // [p][64] bf16, swizzled
    const int bid = blockIdx.x;
    const int bb = bid >> 3, hh = bid & 7;
    const int tid  = threadIdx.x;
    const int lane = tid & 63;
    const int w    = tid >> 6;            // 0..3
    const int r15  = lane & 15, g4 = lane >> 4;

    const bf16_t* qB = qb + (long)bid * 8192;
    const bf16_t* kB = kb + (long)bid * 8192;
    const bf16_t* vB = vb + (long)bid * 8192;

    // ---- q fragments (q pre-scaled by SCALE) ----
    bf16x8 Afr[4];
#pragma unroll
    for (int ks = 0; ks < 4; ++ks)
        Afr[ks] = *(const bf16x8*)(qB + (w * 16 + r15) * 128 + ks * 32 + g4 * 8);

    // ---- dots ----
#pragma unroll
    for (int ct = 0; ct < 4; ++ct) {
        int c = ct * 16 + r15;
        f32x4 sA = f32x4{0.f, 0.f, 0.f, 0.f};
#pragma unroll
        for (int ks = 0; ks < 4; ++ks) {
            bf16x8 Bf = *(const bf16x8*)(kB + c * 128 + ks * 32 + g4 * 8);
            sA = mfma16(Afr[ks], Bf, sA);
        }
        if (c < 50) {
#pragma unroll
            for (int j = 0; j < 4; ++j) {
                int qrow = w * 16 + g4 * 4 + j;
                if (qrow < 50) LS[qrow][c] = sA[j];
            }
        }
    }
    fence();

    // ---- rel bias (rolling prefetch): jj = r + qrow - 49 ----
    {
        const bf16_t* rf = relf + lane * 8;
        bf16x8 R0[4];
#pragma unroll
        for (int ks = 0; ks < 4; ++ks) R0[ks] = *(const bf16x8*)(rf + (ks << 9));
        for (int rt = 0; rt < 7; ++rt) {
            bf16x8 R1[4];
            if (rt < 6) {
#pragma unroll
                for (int ks = 0; ks < 4; ++ks)
                    R1[ks] = *(const bf16x8*)(rf + (((rt + 1) * 4 + ks) << 9));
            }
            f32x4 sA = f32x4{0.f, 0.f, 0.f, 0.f};
#pragma unroll
            for (int ks = 0; ks < 4; ++ks) sA = mfma16(Afr[ks], R0[ks], sA);
            int r = rt * 16 + r15;
#pragma unroll
            for (int j = 0; j < 4; ++j) {
                int qrow = w * 16 + g4 * 4 + j;
                int jj = r + qrow - 49;
                if (qrow < 50 && jj >= 0 && jj < 50) LS[qrow][jj] += sA[j];
            }
#pragma unroll
            for (int ks = 0; ks < 4; ++ks) R0[ks] = R1[ks];
        }
    }
    fence();

    // ---- softmax: 4 lanes per row (rows w*16..w*16+15) -> AS ----
    {
        int row = w * 16 + (lane >> 2);
        int quad = lane & 3;
        int hrow = row & 7;
        if (row < 50) {
            float mx = -1e30f;
            for (int jj = quad; jj < 50; jj += 4) mx = fmaxf(mx, LS[row][jj]);
            mx = fmaxf(mx, __shfl_xor(mx, 1));
            mx = fmaxf(mx, __shfl_xor(mx, 2));
            float sum = 0.f;
            for (int jj = quad; jj < 50; jj += 4) {
                float e = __expf(LS[row][jj] - mx);
                LS[row][jj] = e;
                sum += e;
            }
            sum += __shfl_xor(sum, 1);
            sum += __shfl_xor(sum, 2);
            float rs = 1.f / sum;
            for (int jj = quad; jj < 64; jj += 4) {
                float v = (jj < 50) ? LS[row][jj] * rs : 0.f;
                *(bf16_t*)(AS + row * 128 + (((jj >> 3) ^ hrow) << 4) + (jj & 7) * 2) = (bf16_t)v;
            }
        } else {
            for (int jj = quad; jj < 64; jj += 4)
                *(bf16_t*)(AS + row * 128 + (((jj >> 3) ^ hrow) << 4) + (jj & 7) * 2) = (bf16_t)0.f;
        }
    }
    __syncthreads();

    // ---- PV: wave w owns i-tiles {2w, 2w+1}; all 4 p-tiles ----
#pragma unroll
    for (int ii = 0; ii < 2; ++ii) {
        int itile = w * 2 + ii;
        int irow = itile * 16 + r15;
        bf16x8 Av[2];
#pragma unroll
        for (int ks = 0; ks < 2; ++ks)
            Av[ks] = *(const bf16x8*)(vB + irow * 64 + ks * 32 + g4 * 8);
        int dd = itile * 4 + g4;
#pragma unroll
        for (int pt = 0; pt < 4; ++pt) {
            int prow = pt * 16 + r15;
            int hp2 = prow & 7;
            f32x4 po = f32x4{0.f, 0.f, 0.f, 0.f};
#pragma unroll
            for (int ks = 0; ks < 2; ++ks) {
                bf16x8 Bs = *(const bf16x8*)(AS + prow * 128 + ((((ks << 2) | g4) ^ hp2) << 4));
                po = mfma16(Av[ks], Bs, po);
            }
            if (dd < 31 && prow < 50)
                *(f32x4*)(out + ((long)bb * 248 + hh * 31 + dd) * 200 + prow * 4) = po;
        }
    }
}

// ---------------------------------------------------------------------------
extern "C" void kernel_launch(void* const* d_in, const int* in_sizes, int n_in,
                              void* d_out, int out_size, void* d_ws, size_t ws_size,
                              hipStream_t stream)
{
    const float* x   = (const float*)d_in[0];
    const float* wq  = (const float*)d_in[1];
    const float* bq  = (const float*)d_in[2];
    const float* rel = (const float*)d_in[3];
    float* out = (float*)d_out;

    char* ws = (char*)d_ws;
    bf16_t* Wf   = (bf16_t*)ws;                    // 393,216 B
    bf16_t* relf = (bf16_t*)(ws + 393216);         // 28,672 B
    bf16_t* qb   = (bf16_t*)(ws + 421888);         // 512*8*64*128*2 = 64 MiB
    bf16_t* kb   = qb + 33554432L;
    bf16_t* vb   = kb + 33554432L;
    // total: 421,888 + 3*67,108,864 = 201,748,480 B (same as round-1 fit)

    const int B = in_sizes[0] / 49600;

    prep_kernel<<<dim3(824), dim3(256), 0, stream>>>(wq, rel, Wf, relf);
    qkv_kernel<<<dim3(B * 200 / 64), dim3(512), 0, stream>>>(x, bq, Wf, qb, kb, vb);
    attn_kernel<<<dim3(B * 8), dim3(256), 0, stream>>>(qb, kb, vb, relf, out);
}

// Round 9
// 194.777 us; speedup vs baseline: 1.7777x; 1.3706x over previous
//
#include <hip/hip_runtime.h>
#include <hip/hip_bf16.h>
#include <stdint.h>

typedef __bf16 bf16_t;
typedef bf16_t bf16x8 __attribute__((ext_vector_type(8)));
typedef bf16_t bf16x4 __attribute__((ext_vector_type(4)));
typedef float f32x4 __attribute__((ext_vector_type(4)));

// H=8 D=31 T=4 P=50 C=248 O=744 B=512, DT=124, SCALE=31^-0.5
constexpr float SCALE = 0.17960530202677491f;

__device__ __forceinline__ f32x4 mfma16(bf16x8 a, bf16x8 b, f32x4 c) {
    return __builtin_amdgcn_mfma_f32_16x16x32_bf16(a, b, c, 0, 0, 0);
}
__device__ __forceinline__ void fence() {
    asm volatile("s_waitcnt lgkmcnt(0)" ::: "memory");
}
__device__ __forceinline__ void gload_lds16(const void* g, void* l) {
    __builtin_amdgcn_global_load_lds((const __attribute__((address_space(1))) void*)g,
                                     (__attribute__((address_space(3))) void*)l, 16, 0, 0);
}

// ---------------------------------------------------------------------------
// prep: WT[768][256] bf16 row-major (zeros at o>=744, c>=248  -- the zero pad
// is REQUIRED: it annihilates XT's k-pad garbage in the GEMM), relf frag-packed
// (rt 0..6, rows 99..111 zero) for the attn rel-bias GEMM.
// ---------------------------------------------------------------------------
__global__ void prep_kernel(const float* __restrict__ w, const float* __restrict__ rel,
                            bf16_t* __restrict__ WT, bf16_t* __restrict__ relf)
{
    int i = blockIdx.x * 256 + threadIdx.x;
    if (i < 196608) {                    // WT: 768*256
        int o = i >> 8, c = i & 255;
        WT[i] = (o < 744 && c < 248) ? (bf16_t)w[(long)o * 248 + c] : (bf16_t)0.f;
        return;
    }
    i -= 196608;
    if (i < 14336) {                     // relf: rt 0..6 frag blocks
        int e = i & 7, lane = (i >> 3) & 63;
        int f = i >> 9;                  // rt*4+ks
        int ks = f & 3, rt = f >> 2;
        int r = rt * 16 + (lane & 15);
        int dt = ks * 32 + (lane >> 4) * 8 + e;
        float v = 0.f;
        if (r < 99 && dt < 124) v = rel[r * 124 + dt];
        relf[i] = (bf16_t)v;
    }
}

// ---------------------------------------------------------------------------
// xb: transpose+convert x[b][c][n] f32 -> XT[nflat][248] bf16 (rows 496 B).
// Block = 64 flat-n columns. LDS-mediated: strided scalar reads (proven ok),
// then identity dump LDS->global, fully coalesced.
// ---------------------------------------------------------------------------
__global__ void __launch_bounds__(512)
xb_kernel(const float* __restrict__ x, bf16_t* __restrict__ XT)
{
    __shared__ __align__(16) char XS[31744];       // [64 n][248 k] bf16
    const int tid = threadIdx.x;
    const int blk = blockIdx.x;                    // 0..1599
    const int cl = tid & 63;                       // n within block
    const int cg = tid >> 6;                       // 0..7
    {
        int f = blk * 64 + cl;
        int b = f / 200;
        int nn = f - b * 200;
        const float* xp = x + (long)b * 49600 + nn;
#pragma unroll
        for (int ii = 0; ii < 4; ++ii) {
            int cb = cg + 8 * ii;                  // 16B chunk 0..31
            if (cb < 31) {
                bf16x8 pk;
#pragma unroll
                for (int e = 0; e < 8; ++e)
                    pk[e] = (bf16_t)xp[(long)(cb * 8 + e) * 200];
                *(bf16x8*)(XS + cl * 496 + cb * 16) = pk;
            }
        }
    }
    __syncthreads();
    if (tid < 496) {
        char* dst = (char*)XT + (long)blk * 31744 + tid * 64;
#pragma unroll
        for (int j = 0; j < 4; ++j)
            *(f32x4*)(dst + j * 16) = *(const f32x4*)(XS + tid * 64 + j * 16);
    }
}

// ---------------------------------------------------------------------------
// qkv GEMM (m97 template): C[n][o] = XT[n][k] * WT[o][k], 128x128 tile, BK=32,
// 256 thr = 2x2 waves, dbuf LDS via global_load_lds w16, 8 K-steps.
// Epilogue: o->(s,h,d); q/k/v stored [bh][50][128] bf16, q pre-scaled.
// ---------------------------------------------------------------------------
__global__ void __launch_bounds__(256)
qkv_kernel(const bf16_t* __restrict__ XT, const bf16_t* __restrict__ WT,
           const float* __restrict__ bqkv, bf16_t* __restrict__ qkv)
{
    __shared__ __align__(16) char SM[32768];   // A: buf*8192, B: 16384+buf*8192
    const int raw = blockIdx.x;                // 4800 = 8*600
    const int swz = (raw & 7) * 600 + (raw >> 3);
    const int mt = swz % 6, nt = swz / 6;      // nt 0..799
    const int n0 = nt * 128, o0 = mt * 128;
    const int tid  = threadIdx.x;
    const int lane = tid & 63;
    const int wv   = tid >> 6;                 // 0..3
    const int r15  = lane & 15, g4 = lane >> 4;
    const int kc   = lane & 3, rsub = lane >> 2;
    const int wr = wv >> 1, wc = wv & 1;

    f32x4 acc[4][4];
#pragma unroll
    for (int a = 0; a < 4; ++a)
#pragma unroll
        for (int b = 0; b < 4; ++b) acc[a][b] = f32x4{0.f, 0.f, 0.f, 0.f};

    const char* XTb = (const char*)XT;
    const char* WTb = (const char*)WT;

#define STAGE(BUF, KS)                                                          \
    {                                                                           \
        _Pragma("unroll")                                                       \
        for (int i_ = 0; i_ < 2; ++i_) {                                        \
            int r0 = (wv * 2 + i_) * 16;                                        \
            int row = r0 + rsub;                                                \
            gload_lds16(XTb + (long)(n0 + row) * 496 + ((KS) * 4 + kc) * 16,    \
                        SM + (BUF) * 8192 + r0 * 64);                           \
            gload_lds16(WTb + (long)(o0 + row) * 512 + ((KS) * 4 + kc) * 16,    \
                        SM + 16384 + (BUF) * 8192 + r0 * 64);                   \
        }                                                                       \
    }

    STAGE(0, 0);
    __syncthreads();

    int buf = 0;
    for (int ks = 0; ks < 8; ++ks) {
        if (ks < 7) STAGE(buf ^ 1, ks + 1);
        bf16x8 Af[4], Bf[4];
#pragma unroll
        for (int fn = 0; fn < 4; ++fn) {
            int row = wr * 64 + fn * 16 + r15;
            Af[fn] = *(const bf16x8*)(SM + buf * 8192 + row * 64 + g4 * 16);
        }
#pragma unroll
        for (int fo = 0; fo < 4; ++fo) {
            int row = wc * 64 + fo * 16 + r15;
            Bf[fo] = *(const bf16x8*)(SM + 16384 + buf * 8192 + row * 64 + g4 * 16);
        }
#pragma unroll
        for (int fn = 0; fn < 4; ++fn)
#pragma unroll
            for (int fo = 0; fo < 4; ++fo)
                acc[fn][fo] = mfma16(Af[fn], Bf[fo], acc[fn][fo]);
        __syncthreads();
        buf ^= 1;
    }
#undef STAGE

    // ---- epilogue ----
#pragma unroll
    for (int fo = 0; fo < 4; ++fo) {
        int o = o0 + wc * 64 + fo * 16 + r15;
        bool vo = (o < 744);
        int s = (o >= 496) ? 2 : ((o >= 248) ? 1 : 0);
        int rem = o - s * 248;
        int h = rem / 31;
        int d = rem - h * 31;
        float bias = vo ? bqkv[o] : 0.f;
        float sc = (s == 0) ? SCALE : 1.f;
        bf16_t* baseo = qkv + (long)s * 26214400 + d * 4;
#pragma unroll
        for (int fn = 0; fn < 4; ++fn) {
            int n = n0 + wr * 64 + fn * 16 + g4 * 4;
            int b = n / 200;
            int p = (n - b * 200) >> 2;            // t = acc element j
            if (vo) {
                f32x4 a = acc[fn][fo];
                bf16x4 pk = {(bf16_t)((a[0] + bias) * sc), (bf16_t)((a[1] + bias) * sc),
                             (bf16_t)((a[2] + bias) * sc), (bf16_t)((a[3] + bias) * sc)};
                *(bf16x4*)(baseo + ((long)(b * 8 + h) * 50 + p) * 128) = pk;
            }
        }
    }
}

// ---------------------------------------------------------------------------
// Attention: 1 block per (b,h), 256 thr = 4 waves, ~35 KB LDS (4 blocks/CU).
// v[bh][50][128] transposed to LDS vT[i][p] (XOR swizzle); wave-private
// dots + rel scatter + softmax; PV from LDS; one barrier.
// ---------------------------------------------------------------------------
__global__ void __launch_bounds__(256)
attn_kernel(const bf16_t* __restrict__ qkv, const bf16_t* __restrict__ relf,
            float* __restrict__ out)
{
    __shared__ float LS[50][52];
    __shared__ __align__(16) char AS[8192];    // attn[p][64] bf16, swz row&7
    __shared__ __align__(16) char VT[16384];   // vT[128 i][64 p] bf16, swz i&7
    const int bid = blockIdx.x;
    const int bb = bid >> 3, hh = bid & 7;
    const int tid  = threadIdx.x;
    const int lane = tid & 63;
    const int w    = tid >> 6;                 // 0..3
    const int r15  = lane & 15, g4 = lane >> 4;

    const bf16_t* qB = qkv + (long)bid * 6400;
    const bf16_t* kB = qkv + 26214400L + (long)bid * 6400;
    const bf16_t* vB = qkv + 52428800L + (long)bid * 6400;

    // ---- stage v -> vT (LDS), rows p 0..63 (>=50 garbage, killed by AS=0) ----
    {
        int p_ = tid >> 2, cc = tid & 3;
#pragma unroll
        for (int u = 0; u < 4; ++u) {
            int c = cc + u * 4;                // i-chunk 0..15
            bf16x8 vv = *(const bf16x8*)(vB + p_ * 128 + c * 8);
#pragma unroll
            for (int e = 0; e < 8; ++e) {
                int i = c * 8 + e;
                *(bf16_t*)(VT + i * 128 + ((((p_ >> 3) ^ (i & 7))) << 4) + (p_ & 7) * 2) = vv[e];
            }
        }
    }

    // ---- q fragments (pre-scaled) ----
    bf16x8 Afr[4];
#pragma unroll
    for (int ks = 0; ks < 4; ++ks)
        Afr[ks] = *(const bf16x8*)(qB + (w * 16 + r15) * 128 + ks * 32 + g4 * 8);

    // ---- dots ----
#pragma unroll
    for (int ct = 0; ct < 4; ++ct) {
        int c = ct * 16 + r15;
        f32x4 sA = f32x4{0.f, 0.f, 0.f, 0.f};
#pragma unroll
        for (int ks = 0; ks < 4; ++ks) {
            bf16x8 Bf = *(const bf16x8*)(kB + c * 128 + ks * 32 + g4 * 8);
            sA = mfma16(Afr[ks], Bf, sA);
        }
        if (c < 50) {
#pragma unroll
            for (int j = 0; j < 4; ++j) {
                int qrow = w * 16 + g4 * 4 + j;
                if (qrow < 50) LS[qrow][c] = sA[j];
            }
        }
    }
    fence();

    // ---- rel bias (rolling prefetch): jj = r + qrow - 49 ----
    {
        const bf16_t* rf = relf + lane * 8;
        bf16x8 R0[4];
#pragma unroll
        for (int ks = 0; ks < 4; ++ks) R0[ks] = *(const bf16x8*)(rf + (ks << 9));
        for (int rt = 0; rt < 7; ++rt) {
            bf16x8 R1[4];
            if (rt < 6) {
#pragma unroll
                for (int ks = 0; ks < 4; ++ks)
                    R1[ks] = *(const bf16x8*)(rf + (((rt + 1) * 4 + ks) << 9));
            }
            f32x4 sA = f32x4{0.f, 0.f, 0.f, 0.f};
#pragma unroll
            for (int ks = 0; ks < 4; ++ks) sA = mfma16(Afr[ks], R0[ks], sA);
            int r = rt * 16 + r15;
#pragma unroll
            for (int j = 0; j < 4; ++j) {
                int qrow = w * 16 + g4 * 4 + j;
                int jj = r + qrow - 49;
                if (qrow < 50 && jj >= 0 && jj < 50) LS[qrow][jj] += sA[j];
            }
#pragma unroll
            for (int ks = 0; ks < 4; ++ks) R0[ks] = R1[ks];
        }
    }
    fence();

    // ---- softmax: 4 lanes per row (rows w*16..w*16+15) -> AS ----
    {
        int row = w * 16 + (lane >> 2);
        int quad = lane & 3;
        int hrow = row & 7;
        if (row < 50) {
            float mx = -1e30f;
            for (int jj = quad; jj < 50; jj += 4) mx = fmaxf(mx, LS[row][jj]);
            mx = fmaxf(mx, __shfl_xor(mx, 1));
            mx = fmaxf(mx, __shfl_xor(mx, 2));
            float sum = 0.f;
            for (int jj = quad; jj < 50; jj += 4) {
                float e = __expf(LS[row][jj] - mx);
                LS[row][jj] = e;
                sum += e;
            }
            sum += __shfl_xor(sum, 1);
            sum += __shfl_xor(sum, 2);
            float rs = 1.f / sum;
            for (int jj = quad; jj < 64; jj += 4) {
                float v = (jj < 50) ? LS[row][jj] * rs : 0.f;
                *(bf16_t*)(AS + row * 128 + (((jj >> 3) ^ hrow) << 4) + (jj & 7) * 2) = (bf16_t)v;
            }
        } else {
            for (int jj = quad; jj < 64; jj += 4)
                *(bf16_t*)(AS + row * 128 + (((jj >> 3) ^ hrow) << 4) + (jj & 7) * 2) = (bf16_t)0.f;
        }
    }
    __syncthreads();   // AS + VT ready

    // ---- PV: wave w owns i-tiles {2w, 2w+1}; all 4 p-tiles ----
#pragma unroll
    for (int ii = 0; ii < 2; ++ii) {
        int itile = w * 2 + ii;
        int irow = itile * 16 + r15;
        bf16x8 Av[2];
#pragma unroll
        for (int ks = 0; ks < 2; ++ks)
            Av[ks] = *(const bf16x8*)(VT + irow * 128 + ((((ks * 4) + g4) ^ (irow & 7)) << 4));
        int dd = itile * 4 + g4;
#pragma unroll
        for (int pt = 0; pt < 4; ++pt) {
            int prow = pt * 16 + r15;
            int hp2 = prow & 7;
            f32x4 po = f32x4{0.f, 0.f, 0.f, 0.f};
#pragma unroll
            for (int ks = 0; ks < 2; ++ks) {
                bf16x8 Bs = *(const bf16x8*)(AS + prow * 128 + ((((ks * 4) + g4) ^ hp2) << 4));
                po = mfma16(Av[ks], Bs, po);
            }
            if (dd < 31 && prow < 50)
                *(f32x4*)(out + ((long)bb * 248 + hh * 31 + dd) * 200 + prow * 4) = po;
        }
    }
}

// ---------------------------------------------------------------------------
extern "C" void kernel_launch(void* const* d_in, const int* in_sizes, int n_in,
                              void* d_out, int out_size, void* d_ws, size_t ws_size,
                              hipStream_t stream)
{
    const float* x   = (const float*)d_in[0];
    const float* wq  = (const float*)d_in[1];
    const float* bq  = (const float*)d_in[2];
    const float* rel = (const float*)d_in[3];
    float* out = (float*)d_out;

    char* ws = (char*)d_ws;
    bf16_t* WT   = (bf16_t*)ws;                    // 393,216 B
    bf16_t* relf = (bf16_t*)(ws + 393216);         // 28,672 B
    bf16_t* qkv  = (bf16_t*)(ws + 421888);         // 3 x 52,428,800 B = 157.3 MB
    // ws used: 157,708,288 B  (< R1-proven 201.7 MB)

    // XT lives in d_out (50.79 MB of 101.58 MB); attn fully overwrites out.
    bf16_t* XT = (bf16_t*)d_out;

    const int B = in_sizes[0] / 49600;             // 512

    prep_kernel<<<dim3(824), dim3(256), 0, stream>>>(wq, rel, WT, relf);
    xb_kernel<<<dim3(B * 200 / 64), dim3(512), 0, stream>>>(x, XT);
    qkv_kernel<<<dim3(4800), dim3(256), 0, stream>>>(XT, WT, bq, qkv);
    attn_kernel<<<dim3(B * 8), dim3(256), 0, stream>>>(qkv, relf, out);
}